// Round 9
// baseline (117.249 us; speedup 1.0000x reference)
//
#include <hip/hip_runtime.h>
#include <stdint.h>

// Causal self-attention: x[8,2048,256] fp32, W_attn[768,256], W_proj[256,256]
// cvt->bf16 (fused), QKV GEMM writing FRAGMENT-CONTIGUOUS Qf/Kf/Vf layouts
// (K pre-scaled by 1/sqrt(D)*log2e), flash attn: 32x32x16 MFMA, swapped QK,
// in-register softmax, 4 waves/block sharing KV tiles in lockstep (L1 reuse).
// proj GEMM.
//
// Fragment layouts (per bh, 131072 elems):
//  Qf: [chunk32][sblk=d>>4][q&31][d&15]
//  Kf: [tile64][sblk=d>>4][key&63][d&15]
//  Vf: [tile64][kblk=(s>>4)&3][d][s&15]
// Wave load for any fragment: contiguous 1KB, lane offset = l31*16 + hi*8.

#define BB 8
#define SS 2048
#define CC 256
#define HH 4
#define DD 64

typedef __attribute__((ext_vector_type(8))) __bf16 bf16x8;
typedef __attribute__((ext_vector_type(4))) __bf16 bf16x4;
typedef __attribute__((ext_vector_type(4))) float f32x4;
typedef __attribute__((ext_vector_type(16))) float f32x16;

#define CM 0.18033688011112042f   // (1/sqrt(64)) * log2(e), folded into K

static __device__ __forceinline__ uint32_t cvtpk(float lo, float hi) {
  uint32_t r;
  asm("v_cvt_pk_bf16_f32 %0, %1, %2" : "=v"(r) : "v"(lo), "v"(hi));
  return r;
}
static __device__ __forceinline__ void pl32swap(uint32_t& a, uint32_t& b) {
  asm("v_permlane32_swap_b32 %0, %1" : "+v"(a), "+v"(b));
}
union PU { uint32_t u[4]; bf16x8 v; };

// ---------------- fused fp32 -> bf16 convert (x, W_attn, W_proj) ------------
__global__ __launch_bounds__(256) void cvt3_kernel(const float* __restrict__ x,
                                                   const float* __restrict__ wa,
                                                   const float* __restrict__ wp,
                                                   __bf16* __restrict__ xb,
                                                   __bf16* __restrict__ wab,
                                                   __bf16* __restrict__ wpb) {
  int i = blockIdx.x * blockDim.x + threadIdx.x;
  const float* in; __bf16* out;
  if (i < 1048576) { in = x; out = xb; }
  else if (i < 1048576 + 49152) { i -= 1048576; in = wa; out = wab; }
  else { i -= 1048576 + 49152; in = wp; out = wpb; }
  float4 v = ((const float4*)in)[i];
  bf16x4 o = { (__bf16)v.x, (__bf16)v.y, (__bf16)v.z, (__bf16)v.w };
  *(bf16x4*)(out + 4 * i) = o;
}

// ---------------- QKV GEMM: qkv = x @ W_attn^T -> Qf/Kf/Vf ----------------
__global__ __launch_bounds__(256) void qkv_gemm(const __bf16* __restrict__ xb,
                                                const __bf16* __restrict__ wb,
                                                __bf16* __restrict__ qf_,
                                                __bf16* __restrict__ kf_,
                                                __bf16* __restrict__ vf_) {
  const int lane = threadIdx.x & 63;
  const int ln = lane & 15, kg = lane >> 4;
  const int w = threadIdx.x >> 6;
  const int otile = blockIdx.x % 12;
  const int r0 = (blockIdx.x / 12) * 256 + w * 64;
  const int o0 = otile * 64;

  f32x4 acc[4][4] = {};
  for (int c0 = 0; c0 < CC; c0 += 32) {
    bf16x8 a[4], wv[4];
#pragma unroll
    for (int i = 0; i < 4; ++i)
      a[i] = *(const bf16x8*)(xb + (r0 + i * 16 + ln) * CC + c0 + kg * 8);
#pragma unroll
    for (int t = 0; t < 4; ++t)
      wv[t] = *(const bf16x8*)(wb + (o0 + t * 16 + ln) * CC + c0 + kg * 8);
#pragma unroll
    for (int i = 0; i < 4; ++i)
#pragma unroll
      for (int t = 0; t < 4; ++t)
        acc[i][t] = __builtin_amdgcn_mfma_f32_16x16x32_bf16(a[i], wv[t], acc[i][t], 0, 0, 0);
  }
#pragma unroll
  for (int i = 0; i < 4; ++i)
#pragma unroll
    for (int t = 0; t < 4; ++t) {
      int o = o0 + t * 16 + ln;
      int sel = o >> 8;         // 0=q 1=k 2=v
      int oo = o & 255;
      int h = oo >> 6, d = oo & 63;
#pragma unroll
      for (int r = 0; r < 4; ++r) {
        int rout = r0 + i * 16 + kg * 4 + r;
        int b = rout >> 11, s = rout & 2047;
        int bh = (b * HH + h) * 131072;
        if (sel == 0) {
          int off = bh + (s >> 5) * 2048 + (d >> 4) * 512 + (s & 31) * 16 + (d & 15);
          qf_[off] = (__bf16)acc[i][t][r];
        } else if (sel == 1) {
          int off = bh + (s >> 6) * 4096 + (d >> 4) * 1024 + (s & 63) * 16 + (d & 15);
          kf_[off] = (__bf16)(acc[i][t][r] * CM);
        } else {
          int off = bh + (s >> 6) * 4096 + ((s >> 4) & 3) * 1024 + d * 16 + (s & 15);
          vf_[off] = (__bf16)acc[i][t][r];
        }
      }
    }
}

// ---------------- Flash attention ----------------
// 512 blocks x 4 waves = 128 q-rows/block. The 4 waves own chunks 4cg..4cg+3
// and walk the SAME key tiles in lockstep (barrier per tile) so the 16KB KV
// tile is fetched once to L1 and reused 4x. Waves past their causal limit
// skip compute. Dispatch pairs long/short chunk-groups for balance.
__global__ __launch_bounds__(256, 3) void attn_kernel(const __bf16* __restrict__ qf_,
                                                      const __bf16* __restrict__ kf_,
                                                      const __bf16* __restrict__ vf_,
                                                      __bf16* __restrict__ yb) {
  const int lane = threadIdx.x & 63;
  const int l31 = lane & 31;
  const int hi = lane >> 5;
  const int w = threadIdx.x >> 6;      // 0..3

  const int bid = blockIdx.x;
  const int xs = bid & 7;              // XCD slot
  const int j = bid >> 3;              // 0..63
  const int bh = xs + 8 * (j & 3);     // 4 bh per XCD -> 2MB KV in L2
  const int k4 = j >> 2;               // 0..15
  const int cg = (k4 & 1) ? (k4 >> 1) : (15 - (k4 >> 1));  // pair long/short
  const int c = cg * 4 + w;            // this wave's 32-q chunk
  const int q0w = c * 32;
  const int q = q0w + l31;

  const int loff = l31 * 16 + hi * 8;  // lane offset within any 1KB fragment

  const __bf16* Qfb = qf_ + bh * 131072 + c * 2048 + loff;
  const __bf16* Kb  = kf_ + bh * 131072 + loff;
  const __bf16* Vb  = vf_ + bh * 131072 + loff;

  bf16x8 qf[4];
#pragma unroll
  for (int s = 0; s < 4; ++s) qf[s] = *(const bf16x8*)(Qfb + s * 512);

  const int ntot = (q0w + 95) >> 6;    // this wave's 64-key tiles; last = diag
  const int ntb = 2 * cg + 2;          // block max tiles (chunk cg*4+3)
  const int qrel = l31 + 32 * (c & 1);

  f32x16 acc0 = {}, acc1 = {};
  float mrun = -1e30f, lrun = 0.0f;

  // K fragments for tile 0 (all waves: same addresses -> L1 broadcast)
  bf16x8 ka[2][4];
#pragma unroll
  for (int s = 0; s < 4; ++s) {
    ka[0][s] = *(const bf16x8*)(Kb + s * 1024);
    ka[1][s] = *(const bf16x8*)(Kb + s * 1024 + 512);
  }

  for (int kt = 0; kt < ntb; ++kt) {
    __syncthreads();                   // keep waves on the same KV tile (L1 reuse)
    if (kt < ntot) {
      // V loads (coalesced fragment bursts)
      bf16x8 vf0[4], vf1[4];
      {
        const __bf16* Vp = Vb + kt * 4096;
#pragma unroll
        for (int s = 0; s < 4; ++s) {
          vf0[s] = *(const bf16x8*)(Vp + s * 1024);
          vf1[s] = *(const bf16x8*)(Vp + s * 1024 + 512);
        }
      }

      // QK^T (swapped): s0 = keys kbase..+31, s1 = +32..63; cols = q
      f32x16 s0 = {}, s1 = {};
      __builtin_amdgcn_s_setprio(1);
#pragma unroll
      for (int s = 0; s < 4; ++s) s0 = __builtin_amdgcn_mfma_f32_32x32x16_bf16(ka[0][s], qf[s], s0, 0, 0, 0);
#pragma unroll
      for (int s = 0; s < 4; ++s) s1 = __builtin_amdgcn_mfma_f32_32x32x16_bf16(ka[1][s], qf[s], s1, 0, 0, 0);
      __builtin_amdgcn_s_setprio(0);

      // prefetch next K tile
      {
        const int pb = (kt + 1 < ntot) ? (kt + 1) : kt;
        const __bf16* Kn = Kb + pb * 4096;
#pragma unroll
        for (int s = 0; s < 4; ++s) {
          ka[0][s] = *(const bf16x8*)(Kn + s * 1024);
          ka[1][s] = *(const bf16x8*)(Kn + s * 1024 + 512);
        }
      }

      float p[32];
#pragma unroll
      for (int r = 0; r < 16; ++r) { p[r] = s0[r]; p[16 + r] = s1[r]; }
      if (kt == ntot - 1) {             // diagonal tile: per-lane causal mask
#pragma unroll
        for (int r = 0; r < 16; ++r) {
          int crow = (r & 3) + 8 * (r >> 2) + 4 * hi;
          p[r]      = (crow      <= qrel) ? p[r]      : -1e30f;
          p[16 + r] = (crow + 32 <= qrel) ? p[16 + r] : -1e30f;
        }
      }

      // row max (tree) + cross-half
      float mx[16];
#pragma unroll
      for (int r = 0; r < 16; ++r) mx[r] = fmaxf(p[r], p[16 + r]);
#pragma unroll
      for (int st = 8; st > 0; st >>= 1)
#pragma unroll
        for (int r = 0; r < 8; ++r) if (r < st) mx[r] = fmaxf(mx[r], mx[r + st]);
      float tmax = fmaxf(mx[0], __shfl_xor(mx[0], 32));

      if (!__all(tmax <= mrun)) {       // exact defer: rescale only on new max
        float mnew = fmaxf(mrun, tmax);
        float al = __builtin_amdgcn_exp2f(mrun - mnew);
        mrun = mnew;
        lrun *= al;
        acc0 *= al;
        acc1 *= al;
      }
#pragma unroll
      for (int r = 0; r < 32; ++r) p[r] = __builtin_amdgcn_exp2f(p[r] - mrun);

      // row sum (tree) + cross-half
      float sm[16];
#pragma unroll
      for (int r = 0; r < 16; ++r) sm[r] = p[r] + p[16 + r];
#pragma unroll
      for (int st = 8; st > 0; st >>= 1)
#pragma unroll
        for (int r = 0; r < 8; ++r) if (r < st) sm[r] += sm[r + st];
      lrun += sm[0] + __shfl_xor(sm[0], 32);

      // repack P -> B-fragments: cvt_pk + permlane32_swap (no LDS)
      bf16x8 pf[4];
#pragma unroll
      for (int g = 0; g < 4; ++g) {
        const int o = (g >> 1) * 16 + (g & 1) * 8;
        uint32_t a = cvtpk(p[o + 0], p[o + 1]);
        uint32_t b = cvtpk(p[o + 4], p[o + 5]);
        uint32_t c2 = cvtpk(p[o + 2], p[o + 3]);
        uint32_t d2 = cvtpk(p[o + 6], p[o + 7]);
        pl32swap(a, b);
        pl32swap(c2, d2);
        PU u; u.u[0] = a; u.u[1] = c2; u.u[2] = b; u.u[3] = d2;
        pf[g] = u.v;
      }

      // PV: acc[dg] += V^T[dg] . P
      __builtin_amdgcn_s_setprio(1);
#pragma unroll
      for (int g = 0; g < 4; ++g) acc0 = __builtin_amdgcn_mfma_f32_32x32x16_bf16(vf0[g], pf[g], acc0, 0, 0, 0);
#pragma unroll
      for (int g = 0; g < 4; ++g) acc1 = __builtin_amdgcn_mfma_f32_32x32x16_bf16(vf1[g], pf[g], acc1, 0, 0, 0);
      __builtin_amdgcn_s_setprio(0);
    }
  }

  // epilogue: each wave writes its own 32 rows
  const int b = bh >> 2, h = bh & 3;
  __bf16* yrow = yb + (b * SS + q) * CC + h * DD;
  float inv = __builtin_amdgcn_rcpf(lrun);
#pragma unroll
  for (int g = 0; g < 4; ++g) {
    {
      uint32_t w0 = cvtpk(acc0[g * 4 + 0] * inv, acc0[g * 4 + 1] * inv);
      uint32_t w1 = cvtpk(acc0[g * 4 + 2] * inv, acc0[g * 4 + 3] * inv);
      uint2 st = { w0, w1 };
      *(uint2*)(yrow + g * 8 + hi * 4) = st;
    }
    {
      uint32_t w0 = cvtpk(acc1[g * 4 + 0] * inv, acc1[g * 4 + 1] * inv);
      uint32_t w1 = cvtpk(acc1[g * 4 + 2] * inv, acc1[g * 4 + 3] * inv);
      uint2 st = { w0, w1 };
      *(uint2*)(yrow + 32 + g * 8 + hi * 4) = st;
    }
  }
}

// ---------------- Proj GEMM: out = y @ W_proj^T (fp32 out) ------------------
__global__ __launch_bounds__(256) void proj_gemm(const __bf16* __restrict__ yb,
                                                 const __bf16* __restrict__ wpb,
                                                 float* __restrict__ out) {
  const int lane = threadIdx.x & 63;
  const int ln = lane & 15, kg = lane >> 4;
  const int w = threadIdx.x >> 6;
  const int otile = blockIdx.x & 3;
  const int r0 = (blockIdx.x >> 2) * 256 + w * 64;
  const int o0 = otile * 64;

  f32x4 acc[4][4] = {};
  for (int c0 = 0; c0 < CC; c0 += 32) {
    bf16x8 a[4], wv[4];
#pragma unroll
    for (int i = 0; i < 4; ++i)
      a[i] = *(const bf16x8*)(yb + (r0 + i * 16 + ln) * CC + c0 + kg * 8);
#pragma unroll
    for (int t = 0; t < 4; ++t)
      wv[t] = *(const bf16x8*)(wpb + (o0 + t * 16 + ln) * CC + c0 + kg * 8);
#pragma unroll
    for (int i = 0; i < 4; ++i)
#pragma unroll
      for (int t = 0; t < 4; ++t)
        acc[i][t] = __builtin_amdgcn_mfma_f32_16x16x32_bf16(a[i], wv[t], acc[i][t], 0, 0, 0);
  }
#pragma unroll
  for (int i = 0; i < 4; ++i)
#pragma unroll
    for (int t = 0; t < 4; ++t) {
      int o = o0 + t * 16 + ln;
#pragma unroll
      for (int r = 0; r < 4; ++r) {
        int rout = r0 + i * 16 + kg * 4 + r;
        out[rout * 256 + o] = acc[i][t][r];
      }
    }
}

extern "C" void kernel_launch(void* const* d_in, const int* in_sizes, int n_in,
                              void* d_out, int out_size, void* d_ws, size_t ws_size,
                              hipStream_t stream) {
  const float* x = (const float*)d_in[0];
  const float* Wa = (const float*)d_in[1];
  const float* Wp = (const float*)d_in[2];

  char* ws = (char*)d_ws;
  __bf16* xb  = (__bf16*)(ws);                    // 8 MiB  [B*S][C]
  __bf16* qfb = (__bf16*)(ws + 8388608);          // 8 MiB  Qf fragment layout
  __bf16* kfb = (__bf16*)(ws + 16777216);         // 8 MiB  Kf (pre-scaled)
  __bf16* vfb = (__bf16*)(ws + 25165824);         // 8 MiB  Vf
  __bf16* yb  = (__bf16*)(ws + 33554432);         // 8 MiB  [B,S,C]
  __bf16* wab = (__bf16*)(ws + 41943040);         // 384 KiB [768][256]
  __bf16* wpb = (__bf16*)(ws + 42336256);         // 128 KiB [256][256]

  cvt3_kernel<<<4352, 256, 0, stream>>>(x, Wa, Wp, xb, wab, wpb);
  qkv_gemm<<<768, 256, 0, stream>>>(xb, wab, qfb, kfb, vfb);
  attn_kernel<<<512, 256, 0, stream>>>(qfb, kfb, vfb, yb);
  proj_gemm<<<256, 256, 0, stream>>>(yb, wpb, (float*)d_out);
}

// Round 10
// 90.977 us; speedup vs baseline: 1.2888x; 1.2888x over previous
//
#include <hip/hip_runtime.h>
#include <stdint.h>

// Causal self-attention: x[8,2048,256] fp32, W_attn[768,256], W_proj[256,256]
// cvt->bf16 (fused), QKV GEMM writing FRAGMENT-CONTIGUOUS Qf/Kf/Vf layouts
// (K pre-scaled by 1/sqrt(D)*log2e), flash attn: 32x32x16 MFMA, swapped QK,
// in-place in-register softmax, 2-way split-K + LDS combine (R8 geometry).
// XCD-local block swizzle on both GEMMs. proj GEMM.
//
// Fragment layouts (per bh, 131072 elems):
//  Qf: [chunk32][sblk=d>>4][q&31][d&15]
//  Kf: [tile64][sblk=d>>4][key&63][d&15]
//  Vf: [tile64][kblk=(s>>4)&3][d][s&15]
// Wave load for any fragment: contiguous 1KB, lane offset = l31*16 + hi*8.

#define BB 8
#define SS 2048
#define CC 256
#define HH 4
#define DD 64

typedef __attribute__((ext_vector_type(8))) __bf16 bf16x8;
typedef __attribute__((ext_vector_type(4))) __bf16 bf16x4;
typedef __attribute__((ext_vector_type(4))) float f32x4;
typedef __attribute__((ext_vector_type(16))) float f32x16;

#define CM 0.18033688011112042f   // (1/sqrt(64)) * log2(e), folded into K

static __device__ __forceinline__ uint32_t cvtpk(float lo, float hi) {
  uint32_t r;
  asm("v_cvt_pk_bf16_f32 %0, %1, %2" : "=v"(r) : "v"(lo), "v"(hi));
  return r;
}
static __device__ __forceinline__ void pl32swap(uint32_t& a, uint32_t& b) {
  asm("v_permlane32_swap_b32 %0, %1" : "+v"(a), "+v"(b));
}
union PU { uint32_t u[4]; bf16x8 v; };

// ---------------- fused fp32 -> bf16 convert (x, W_attn, W_proj) ------------
__global__ __launch_bounds__(256) void cvt3_kernel(const float* __restrict__ x,
                                                   const float* __restrict__ wa,
                                                   const float* __restrict__ wp,
                                                   __bf16* __restrict__ xb,
                                                   __bf16* __restrict__ wab,
                                                   __bf16* __restrict__ wpb) {
  int i = blockIdx.x * blockDim.x + threadIdx.x;
  const float* in; __bf16* out;
  if (i < 1048576) { in = x; out = xb; }
  else if (i < 1048576 + 49152) { i -= 1048576; in = wa; out = wab; }
  else { i -= 1048576 + 49152; in = wp; out = wpb; }
  float4 v = ((const float4*)in)[i];
  bf16x4 o = { (__bf16)v.x, (__bf16)v.y, (__bf16)v.z, (__bf16)v.w };
  *(bf16x4*)(out + 4 * i) = o;
}

// ---------------- QKV GEMM: qkv = x @ W_attn^T -> Qf/Kf/Vf ----------------
// XCD-local swizzle: each XCD owns 8 contiguous row-groups for ALL 12 otiles,
// so its 128KB x-slice stays in its own L2 across the 12 consecutive blocks.
__global__ __launch_bounds__(256) void qkv_gemm(const __bf16* __restrict__ xb,
                                                const __bf16* __restrict__ wb,
                                                __bf16* __restrict__ qf_,
                                                __bf16* __restrict__ kf_,
                                                __bf16* __restrict__ vf_) {
  const int lane = threadIdx.x & 63;
  const int ln = lane & 15, kg = lane >> 4;
  const int w = threadIdx.x >> 6;
  const int xs = blockIdx.x & 7;
  const int j = blockIdx.x >> 3;           // 0..95
  const int otile = j % 12;
  const int r0 = (xs * 8 + j / 12) * 256 + w * 64;
  const int o0 = otile * 64;

  f32x4 acc[4][4] = {};
  for (int c0 = 0; c0 < CC; c0 += 32) {
    bf16x8 a[4], wv[4];
#pragma unroll
    for (int i = 0; i < 4; ++i)
      a[i] = *(const bf16x8*)(xb + (r0 + i * 16 + ln) * CC + c0 + kg * 8);
#pragma unroll
    for (int t = 0; t < 4; ++t)
      wv[t] = *(const bf16x8*)(wb + (o0 + t * 16 + ln) * CC + c0 + kg * 8);
#pragma unroll
    for (int i = 0; i < 4; ++i)
#pragma unroll
      for (int t = 0; t < 4; ++t)
        acc[i][t] = __builtin_amdgcn_mfma_f32_16x16x32_bf16(a[i], wv[t], acc[i][t], 0, 0, 0);
  }
#pragma unroll
  for (int i = 0; i < 4; ++i)
#pragma unroll
    for (int t = 0; t < 4; ++t) {
      int o = o0 + t * 16 + ln;
      int sel = o >> 8;         // 0=q 1=k 2=v
      int oo = o & 255;
      int h = oo >> 6, d = oo & 63;
#pragma unroll
      for (int r = 0; r < 4; ++r) {
        int rout = r0 + i * 16 + kg * 4 + r;
        int b = rout >> 11, s = rout & 2047;
        int bh = (b * HH + h) * 131072;
        if (sel == 0) {
          int off = bh + (s >> 5) * 2048 + (d >> 4) * 512 + (s & 31) * 16 + (d & 15);
          qf_[off] = (__bf16)acc[i][t][r];
        } else if (sel == 1) {
          int off = bh + (s >> 6) * 4096 + (d >> 4) * 1024 + (s & 63) * 16 + (d & 15);
          kf_[off] = (__bf16)(acc[i][t][r] * CM);
        } else {
          int off = bh + (s >> 6) * 4096 + ((s >> 4) & 3) * 1024 + d * 16 + (s & 15);
          vf_[off] = (__bf16)acc[i][t][r];
        }
      }
    }
}

// ---------------- Flash attention (R8 geometry, in-place softmax) -----------
// 2048 blocks x 2 waves. Block owns one 32-q chunk; waves split the key range
// into contiguous halves (partials merged via LDS). All loads 1KB-coalesced.
__global__ __launch_bounds__(128, 3) void attn_kernel(const __bf16* __restrict__ qf_,
                                                      const __bf16* __restrict__ kf_,
                                                      const __bf16* __restrict__ vf_,
                                                      __bf16* __restrict__ yb) {
  __shared__ float lm[2][32];
  __shared__ float lacc[64][33];
  const int lane = threadIdx.x & 63;
  const int l31 = lane & 31;
  const int hi = lane >> 5;
  const int w = threadIdx.x >> 6;      // 0 or 1

  const int bid = blockIdx.x;
  const int xs = bid & 7;              // XCD slot
  const int j = bid >> 3;              // 0..255
  const int bh = xs + 8 * (j & 3);     // 4 bh per XCD -> 4MB KV in L2
  const int c = 63 - (j >> 2);         // longest chunks first
  const int q0w = c * 32;
  const int q = q0w + l31;

  const int loff = l31 * 16 + hi * 8;  // lane offset within any 1KB fragment

  const __bf16* Qfb = qf_ + bh * 131072 + c * 2048 + loff;
  const __bf16* Kb  = kf_ + bh * 131072 + loff;
  const __bf16* Vb  = vf_ + bh * 131072 + loff;

  bf16x8 qf[4];
#pragma unroll
  for (int s = 0; s < 4; ++s) qf[s] = *(const bf16x8*)(Qfb + s * 512);

  const int ntot = (q0w + 95) >> 6;    // 64-key tiles; last = diagonal
  const int seg = (ntot + 1) >> 1;
  const int kt0 = w * seg;
  const int kt1 = min(kt0 + seg, ntot);
  const int qrel = l31 + 32 * (c & 1);

  f32x16 acc0 = {}, acc1 = {};
  float mrun = -1e30f, lrun = 0.0f;

  if (kt0 < kt1) {
    // K fragments for first tile
    bf16x8 ka[2][4];
    {
      const __bf16* Kp = Kb + kt0 * 4096;
#pragma unroll
      for (int s = 0; s < 4; ++s) {
        ka[0][s] = *(const bf16x8*)(Kp + s * 1024);
        ka[1][s] = *(const bf16x8*)(Kp + s * 1024 + 512);
      }
    }

    for (int kt = kt0; kt < kt1; ++kt) {
      // V loads (coalesced fragment bursts)
      bf16x8 vf0[4], vf1[4];
      {
        const __bf16* Vp = Vb + kt * 4096;
#pragma unroll
        for (int s = 0; s < 4; ++s) {
          vf0[s] = *(const bf16x8*)(Vp + s * 1024);
          vf1[s] = *(const bf16x8*)(Vp + s * 1024 + 512);
        }
      }

      // QK^T (swapped): s0 = keys kbase..+31, s1 = +32..63; cols = q
      f32x16 s0 = {}, s1 = {};
      __builtin_amdgcn_s_setprio(1);
#pragma unroll
      for (int s = 0; s < 4; ++s) s0 = __builtin_amdgcn_mfma_f32_32x32x16_bf16(ka[0][s], qf[s], s0, 0, 0, 0);
#pragma unroll
      for (int s = 0; s < 4; ++s) s1 = __builtin_amdgcn_mfma_f32_32x32x16_bf16(ka[1][s], qf[s], s1, 0, 0, 0);
      __builtin_amdgcn_s_setprio(0);

      // prefetch next K tile
      {
        const int pb = (kt + 1 < kt1) ? (kt + 1) : kt;
        const __bf16* Kn = Kb + pb * 4096;
#pragma unroll
        for (int s = 0; s < 4; ++s) {
          ka[0][s] = *(const bf16x8*)(Kn + s * 1024);
          ka[1][s] = *(const bf16x8*)(Kn + s * 1024 + 512);
        }
      }

      if (kt == ntot - 1) {               // diagonal tile: per-lane causal mask
#pragma unroll
        for (int r = 0; r < 16; ++r) {
          int crow = (r & 3) + 8 * (r >> 2) + 4 * hi;
          s0[r] = (crow      <= qrel) ? s0[r] : -1e30f;
          s1[r] = (crow + 32 <= qrel) ? s1[r] : -1e30f;
        }
      }

      // row max (tree) + cross-half, in-place on s0/s1
      float mx[16];
#pragma unroll
      for (int r = 0; r < 16; ++r) mx[r] = fmaxf(s0[r], s1[r]);
#pragma unroll
      for (int st = 8; st > 0; st >>= 1)
#pragma unroll
        for (int r = 0; r < 8; ++r) if (r < st) mx[r] = fmaxf(mx[r], mx[r + st]);
      float tmax = fmaxf(mx[0], __shfl_xor(mx[0], 32));

      if (!__all(tmax <= mrun)) {         // exact defer: rescale only on new max
        float mnew = fmaxf(mrun, tmax);
        float al = __builtin_amdgcn_exp2f(mrun - mnew);
        mrun = mnew;
        lrun *= al;
        acc0 *= al;
        acc1 *= al;
      }
#pragma unroll
      for (int r = 0; r < 16; ++r) {
        s0[r] = __builtin_amdgcn_exp2f(s0[r] - mrun);
        s1[r] = __builtin_amdgcn_exp2f(s1[r] - mrun);
      }

      // row sum (tree) + cross-half
      float sm[16];
#pragma unroll
      for (int r = 0; r < 16; ++r) sm[r] = s0[r] + s1[r];
#pragma unroll
      for (int st = 8; st > 0; st >>= 1)
#pragma unroll
        for (int r = 0; r < 8; ++r) if (r < st) sm[r] += sm[r + st];
      lrun += sm[0] + __shfl_xor(sm[0], 32);

      // repack P -> B-fragments: cvt_pk + permlane32_swap (no LDS)
      // pf[0]<-s0[0..7], pf[1]<-s0[8..15], pf[2]<-s1[0..7], pf[3]<-s1[8..15]
      bf16x8 pf[4];
#pragma unroll
      for (int g = 0; g < 4; ++g) {
        const f32x16& sv = (g < 2) ? s0 : s1;
        const int o = (g & 1) * 8;
        uint32_t a = cvtpk(sv[o + 0], sv[o + 1]);
        uint32_t b = cvtpk(sv[o + 4], sv[o + 5]);
        uint32_t c2 = cvtpk(sv[o + 2], sv[o + 3]);
        uint32_t d2 = cvtpk(sv[o + 6], sv[o + 7]);
        pl32swap(a, b);
        pl32swap(c2, d2);
        PU u; u.u[0] = a; u.u[1] = c2; u.u[2] = b; u.u[3] = d2;
        pf[g] = u.v;
      }

      // PV: acc[dg] += V^T[dg] . P
      __builtin_amdgcn_s_setprio(1);
#pragma unroll
      for (int g = 0; g < 4; ++g) acc0 = __builtin_amdgcn_mfma_f32_32x32x16_bf16(vf0[g], pf[g], acc0, 0, 0, 0);
#pragma unroll
      for (int g = 0; g < 4; ++g) acc1 = __builtin_amdgcn_mfma_f32_32x32x16_bf16(vf1[g], pf[g], acc1, 0, 0, 0);
      __builtin_amdgcn_s_setprio(0);
    }
  }

  // ---- split-K combine: wave1 -> LDS, wave0 merges + writes y ----
  if (w == 1) {
    if (hi == 0) { lm[0][l31] = mrun; lm[1][l31] = lrun; }
#pragma unroll
    for (int r = 0; r < 16; ++r) {
      int d0 = (r & 3) + 8 * (r >> 2) + 4 * hi;
      lacc[d0][l31] = acc0[r];
      lacc[32 + d0][l31] = acc1[r];
    }
  }
  __syncthreads();
  if (w == 0) {
    float m1 = lm[0][l31], l1 = lm[1][l31];
    float M = fmaxf(mrun, m1);
    float f0 = __builtin_amdgcn_exp2f(mrun - M);
    float f1 = __builtin_amdgcn_exp2f(m1 - M);
    float L = lrun * f0 + l1 * f1;
    float inv = __builtin_amdgcn_rcpf(L);
    const int b = bh >> 2, h = bh & 3;
    __bf16* yrow = yb + (b * SS + q) * CC + h * DD;
#pragma unroll
    for (int g = 0; g < 4; ++g) {
      float a0[4], a1[4];
#pragma unroll
      for (int i2 = 0; i2 < 4; ++i2) {
        int d0 = i2 + 8 * g + 4 * hi;
        a0[i2] = (acc0[g * 4 + i2] * f0 + lacc[d0][l31] * f1) * inv;
        a1[i2] = (acc1[g * 4 + i2] * f0 + lacc[32 + d0][l31] * f1) * inv;
      }
      uint32_t w0 = cvtpk(a0[0], a0[1]);
      uint32_t w1 = cvtpk(a0[2], a0[3]);
      uint2 st0 = { w0, w1 };
      *(uint2*)(yrow + g * 8 + hi * 4) = st0;
      w0 = cvtpk(a1[0], a1[1]);
      w1 = cvtpk(a1[2], a1[3]);
      uint2 st1 = { w0, w1 };
      *(uint2*)(yrow + 32 + g * 8 + hi * 4) = st1;
    }
  }
}

// ---------------- Proj GEMM: out = y @ W_proj^T (fp32 out) ------------------
// XCD-local swizzle: each XCD owns 8 row-groups for all 4 otiles.
__global__ __launch_bounds__(256) void proj_gemm(const __bf16* __restrict__ yb,
                                                 const __bf16* __restrict__ wpb,
                                                 float* __restrict__ out) {
  const int lane = threadIdx.x & 63;
  const int ln = lane & 15, kg = lane >> 4;
  const int w = threadIdx.x >> 6;
  const int xs = blockIdx.x & 7;
  const int j = blockIdx.x >> 3;       // 0..31
  const int otile = j & 3;
  const int r0 = (xs * 8 + (j >> 2)) * 256 + w * 64;
  const int o0 = otile * 64;

  f32x4 acc[4][4] = {};
  for (int c0 = 0; c0 < CC; c0 += 32) {
    bf16x8 a[4], wv[4];
#pragma unroll
    for (int i = 0; i < 4; ++i)
      a[i] = *(const bf16x8*)(yb + (r0 + i * 16 + ln) * CC + c0 + kg * 8);
#pragma unroll
    for (int t = 0; t < 4; ++t)
      wv[t] = *(const bf16x8*)(wpb + (o0 + t * 16 + ln) * CC + c0 + kg * 8);
#pragma unroll
    for (int i = 0; i < 4; ++i)
#pragma unroll
      for (int t = 0; t < 4; ++t)
        acc[i][t] = __builtin_amdgcn_mfma_f32_16x16x32_bf16(a[i], wv[t], acc[i][t], 0, 0, 0);
  }
#pragma unroll
  for (int i = 0; i < 4; ++i)
#pragma unroll
    for (int t = 0; t < 4; ++t) {
      int o = o0 + t * 16 + ln;
#pragma unroll
      for (int r = 0; r < 4; ++r) {
        int rout = r0 + i * 16 + kg * 4 + r;
        out[rout * 256 + o] = acc[i][t][r];
      }
    }
}

extern "C" void kernel_launch(void* const* d_in, const int* in_sizes, int n_in,
                              void* d_out, int out_size, void* d_ws, size_t ws_size,
                              hipStream_t stream) {
  const float* x = (const float*)d_in[0];
  const float* Wa = (const float*)d_in[1];
  const float* Wp = (const float*)d_in[2];

  char* ws = (char*)d_ws;
  __bf16* xb  = (__bf16*)(ws);                    // 8 MiB  [B*S][C]
  __bf16* qfb = (__bf16*)(ws + 8388608);          // 8 MiB  Qf fragment layout
  __bf16* kfb = (__bf16*)(ws + 16777216);         // 8 MiB  Kf (pre-scaled)
  __bf16* vfb = (__bf16*)(ws + 25165824);         // 8 MiB  Vf
  __bf16* yb  = (__bf16*)(ws + 33554432);         // 8 MiB  [B,S,C]
  __bf16* wab = (__bf16*)(ws + 41943040);         // 384 KiB [768][256]
  __bf16* wpb = (__bf16*)(ws + 42336256);         // 128 KiB [256][256]

  cvt3_kernel<<<4352, 256, 0, stream>>>(x, Wa, Wp, xb, wab, wpb);
  qkv_gemm<<<768, 256, 0, stream>>>(xb, wab, qfb, kfb, vfb);
  attn_kernel<<<2048, 128, 0, stream>>>(qfb, kfb, vfb, yb);
  proj_gemm<<<256, 256, 0, stream>>>(yb, wpb, (float*)d_out);
}

// Round 11
// 78.440 us; speedup vs baseline: 1.4948x; 1.1598x over previous
//
#include <hip/hip_runtime.h>
#include <stdint.h>

// Causal self-attention: x[8,2048,256] fp32, W_attn[768,256], W_proj[256,256]
// cvt->bf16 writes MFMA-FRAGMENT-TILE layouts (xf/waf/wpf), QKV GEMM (dense
// 1KB fragment loads; K pre-scaled by 1/sqrt(D)*log2e; outputs Qf/Kf/Vf),
// flash attn (32x32x16 swapped-QK, in-place in-register softmax, 2-way
// split-K + LDS combine; epilogue writes yf fragment tiles), proj GEMM
// (dense fragment loads).
//
// Fragment tile layout (A/B operands, 16x16x32 MFMA): tile = 16 rows x 32
// cols = 512 elems (1KB). off = (tile)*512 + (row&15)*32 + ((c>>3)&3)*8 + (c&7).
// Wave reads one tile as 64 lanes x 16B contiguous (lane off = ln*32+kg*8).
//
// Attn fragment layouts (per bh, 131072 elems):
//  Qf: [chunk32][sblk=d>>4][q&31][d&15]
//  Kf: [tile64][sblk=d>>4][key&63][d&15]
//  Vf: [tile64][kblk=(s>>4)&3][d][s&15]

#define BB 8
#define SS 2048
#define CC 256
#define HH 4
#define DD 64

typedef __attribute__((ext_vector_type(8))) __bf16 bf16x8;
typedef __attribute__((ext_vector_type(4))) __bf16 bf16x4;
typedef __attribute__((ext_vector_type(4))) float f32x4;
typedef __attribute__((ext_vector_type(16))) float f32x16;

#define CM 0.18033688011112042f   // (1/sqrt(64)) * log2(e), folded into K

static __device__ __forceinline__ uint32_t cvtpk(float lo, float hi) {
  uint32_t r;
  asm("v_cvt_pk_bf16_f32 %0, %1, %2" : "=v"(r) : "v"(lo), "v"(hi));
  return r;
}
static __device__ __forceinline__ void pl32swap(uint32_t& a, uint32_t& b) {
  asm("v_permlane32_swap_b32 %0, %1" : "+v"(a), "+v"(b));
}
union PU { uint32_t u[4]; bf16x8 v; };

static __device__ __forceinline__ int frag_off(int row, int c8) {
  // c8 = 8-element column group index (c = c8*8)
  return ((row >> 4) * 8 + (c8 >> 2)) * 512 + (row & 15) * 32 + (c8 & 3) * 8;
}

// ---------------- fused fp32 -> bf16 convert into fragment tiles ------------
// x: 524288 items, wa: 24576, wp: 8192 (8 elems each). 2176 blocks exact.
__global__ __launch_bounds__(256) void cvt3_kernel(const float* __restrict__ x,
                                                   const float* __restrict__ wa,
                                                   const float* __restrict__ wp,
                                                   __bf16* __restrict__ xf,
                                                   __bf16* __restrict__ waf,
                                                   __bf16* __restrict__ wpf) {
  int i = blockIdx.x * blockDim.x + threadIdx.x;
  const float* in; __bf16* out;
  if (i < 524288) {
    in = x + i * 8;
    out = xf + frag_off(i >> 5, i & 31);
  } else if (i < 548864) {
    int j = i - 524288;
    in = wa + j * 8;
    out = waf + frag_off(j >> 5, j & 31);
  } else {
    int k = i - 548864;
    in = wp + k * 8;
    out = wpf + frag_off(k >> 5, k & 31);
  }
  float4 v0 = ((const float4*)in)[0];
  float4 v1 = ((const float4*)in)[1];
  bf16x8 o = { (__bf16)v0.x, (__bf16)v0.y, (__bf16)v0.z, (__bf16)v0.w,
               (__bf16)v1.x, (__bf16)v1.y, (__bf16)v1.z, (__bf16)v1.w };
  *(bf16x8*)out = o;
}

// ---------------- QKV GEMM: qkv = x @ W_attn^T -> Qf/Kf/Vf ----------------
// Dense 1KB fragment loads from xf/waf. XCD-local swizzle on row groups.
__global__ __launch_bounds__(256) void qkv_gemm(const __bf16* __restrict__ xf,
                                                const __bf16* __restrict__ waf,
                                                __bf16* __restrict__ qf_,
                                                __bf16* __restrict__ kf_,
                                                __bf16* __restrict__ vf_) {
  const int lane = threadIdx.x & 63;
  const int ln = lane & 15, kg = lane >> 4;
  const int w = threadIdx.x >> 6;
  const int xs = blockIdx.x & 7;
  const int j = blockIdx.x >> 3;           // 0..95
  const int otile = j % 12;
  const int rt0 = (xs * 8 + j / 12) * 16 + w * 4;   // row-tile (16 rows each)
  const int ot0 = otile * 4;               // W row-tile
  const int loff = ln * 32 + kg * 8;

  f32x4 acc[4][4] = {};
  for (int cb = 0; cb < 8; ++cb) {
    bf16x8 a[4], wv[4];
#pragma unroll
    for (int i = 0; i < 4; ++i)
      a[i] = *(const bf16x8*)(xf + ((rt0 + i) * 8 + cb) * 512 + loff);
#pragma unroll
    for (int t = 0; t < 4; ++t)
      wv[t] = *(const bf16x8*)(waf + ((ot0 + t) * 8 + cb) * 512 + loff);
#pragma unroll
    for (int i = 0; i < 4; ++i)
#pragma unroll
      for (int t = 0; t < 4; ++t)
        acc[i][t] = __builtin_amdgcn_mfma_f32_16x16x32_bf16(a[i], wv[t], acc[i][t], 0, 0, 0);
  }
  const int r0 = rt0 * 16;
  const int o0 = ot0 * 16;
#pragma unroll
  for (int i = 0; i < 4; ++i)
#pragma unroll
    for (int t = 0; t < 4; ++t) {
      int o = o0 + t * 16 + ln;
      int sel = o >> 8;         // 0=q 1=k 2=v
      int oo = o & 255;
      int h = oo >> 6, d = oo & 63;
#pragma unroll
      for (int r = 0; r < 4; ++r) {
        int rout = r0 + i * 16 + kg * 4 + r;
        int b = rout >> 11, s = rout & 2047;
        int bh = (b * HH + h) * 131072;
        if (sel == 0) {
          int off = bh + (s >> 5) * 2048 + (d >> 4) * 512 + (s & 31) * 16 + (d & 15);
          qf_[off] = (__bf16)acc[i][t][r];
        } else if (sel == 1) {
          int off = bh + (s >> 6) * 4096 + (d >> 4) * 1024 + (s & 63) * 16 + (d & 15);
          kf_[off] = (__bf16)(acc[i][t][r] * CM);
        } else {
          int off = bh + (s >> 6) * 4096 + ((s >> 4) & 3) * 1024 + d * 16 + (s & 15);
          vf_[off] = (__bf16)acc[i][t][r];
        }
      }
    }
}

// ---------------- Flash attention (R10 core; epilogue writes yf) ------------
__global__ __launch_bounds__(128, 3) void attn_kernel(const __bf16* __restrict__ qf_,
                                                      const __bf16* __restrict__ kf_,
                                                      const __bf16* __restrict__ vf_,
                                                      __bf16* __restrict__ yf) {
  __shared__ float lm[2][32];
  __shared__ float lacc[64][33];
  const int lane = threadIdx.x & 63;
  const int l31 = lane & 31;
  const int hi = lane >> 5;
  const int w = threadIdx.x >> 6;      // 0 or 1

  const int bid = blockIdx.x;
  const int xs = bid & 7;              // XCD slot
  const int j = bid >> 3;              // 0..255
  const int bh = xs + 8 * (j & 3);     // 4 bh per XCD -> 4MB KV in L2
  const int c = 63 - (j >> 2);         // longest chunks first
  const int q0w = c * 32;
  const int q = q0w + l31;

  const int loff = l31 * 16 + hi * 8;  // lane offset within any 1KB fragment

  const __bf16* Qfb = qf_ + bh * 131072 + c * 2048 + loff;
  const __bf16* Kb  = kf_ + bh * 131072 + loff;
  const __bf16* Vb  = vf_ + bh * 131072 + loff;

  bf16x8 qf[4];
#pragma unroll
  for (int s = 0; s < 4; ++s) qf[s] = *(const bf16x8*)(Qfb + s * 512);

  const int ntot = (q0w + 95) >> 6;    // 64-key tiles; last = diagonal
  const int seg = (ntot + 1) >> 1;
  const int kt0 = w * seg;
  const int kt1 = min(kt0 + seg, ntot);
  const int qrel = l31 + 32 * (c & 1);

  f32x16 acc0 = {}, acc1 = {};
  float mrun = -1e30f, lrun = 0.0f;

  if (kt0 < kt1) {
    bf16x8 ka[2][4];
    {
      const __bf16* Kp = Kb + kt0 * 4096;
#pragma unroll
      for (int s = 0; s < 4; ++s) {
        ka[0][s] = *(const bf16x8*)(Kp + s * 1024);
        ka[1][s] = *(const bf16x8*)(Kp + s * 1024 + 512);
      }
    }

    for (int kt = kt0; kt < kt1; ++kt) {
      bf16x8 vf0[4], vf1[4];
      {
        const __bf16* Vp = Vb + kt * 4096;
#pragma unroll
        for (int s = 0; s < 4; ++s) {
          vf0[s] = *(const bf16x8*)(Vp + s * 1024);
          vf1[s] = *(const bf16x8*)(Vp + s * 1024 + 512);
        }
      }

      f32x16 s0 = {}, s1 = {};
      __builtin_amdgcn_s_setprio(1);
#pragma unroll
      for (int s = 0; s < 4; ++s) s0 = __builtin_amdgcn_mfma_f32_32x32x16_bf16(ka[0][s], qf[s], s0, 0, 0, 0);
#pragma unroll
      for (int s = 0; s < 4; ++s) s1 = __builtin_amdgcn_mfma_f32_32x32x16_bf16(ka[1][s], qf[s], s1, 0, 0, 0);
      __builtin_amdgcn_s_setprio(0);

      {
        const int pb = (kt + 1 < kt1) ? (kt + 1) : kt;
        const __bf16* Kn = Kb + pb * 4096;
#pragma unroll
        for (int s = 0; s < 4; ++s) {
          ka[0][s] = *(const bf16x8*)(Kn + s * 1024);
          ka[1][s] = *(const bf16x8*)(Kn + s * 1024 + 512);
        }
      }

      if (kt == ntot - 1) {               // diagonal tile: per-lane causal mask
#pragma unroll
        for (int r = 0; r < 16; ++r) {
          int crow = (r & 3) + 8 * (r >> 2) + 4 * hi;
          s0[r] = (crow      <= qrel) ? s0[r] : -1e30f;
          s1[r] = (crow + 32 <= qrel) ? s1[r] : -1e30f;
        }
      }

      float mx[16];
#pragma unroll
      for (int r = 0; r < 16; ++r) mx[r] = fmaxf(s0[r], s1[r]);
#pragma unroll
      for (int st = 8; st > 0; st >>= 1)
#pragma unroll
        for (int r = 0; r < 8; ++r) if (r < st) mx[r] = fmaxf(mx[r], mx[r + st]);
      float tmax = fmaxf(mx[0], __shfl_xor(mx[0], 32));

      if (!__all(tmax <= mrun)) {         // exact defer: rescale only on new max
        float mnew = fmaxf(mrun, tmax);
        float al = __builtin_amdgcn_exp2f(mrun - mnew);
        mrun = mnew;
        lrun *= al;
        acc0 *= al;
        acc1 *= al;
      }
#pragma unroll
      for (int r = 0; r < 16; ++r) {
        s0[r] = __builtin_amdgcn_exp2f(s0[r] - mrun);
        s1[r] = __builtin_amdgcn_exp2f(s1[r] - mrun);
      }

      float sm[16];
#pragma unroll
      for (int r = 0; r < 16; ++r) sm[r] = s0[r] + s1[r];
#pragma unroll
      for (int st = 8; st > 0; st >>= 1)
#pragma unroll
        for (int r = 0; r < 8; ++r) if (r < st) sm[r] += sm[r + st];
      lrun += sm[0] + __shfl_xor(sm[0], 32);

      bf16x8 pf[4];
#pragma unroll
      for (int g = 0; g < 4; ++g) {
        const f32x16& sv = (g < 2) ? s0 : s1;
        const int o = (g & 1) * 8;
        uint32_t a = cvtpk(sv[o + 0], sv[o + 1]);
        uint32_t b = cvtpk(sv[o + 4], sv[o + 5]);
        uint32_t c2 = cvtpk(sv[o + 2], sv[o + 3]);
        uint32_t d2 = cvtpk(sv[o + 6], sv[o + 7]);
        pl32swap(a, b);
        pl32swap(c2, d2);
        PU u; u.u[0] = a; u.u[1] = c2; u.u[2] = b; u.u[3] = d2;
        pf[g] = u.v;
      }

      __builtin_amdgcn_s_setprio(1);
#pragma unroll
      for (int g = 0; g < 4; ++g) acc0 = __builtin_amdgcn_mfma_f32_32x32x16_bf16(vf0[g], pf[g], acc0, 0, 0, 0);
#pragma unroll
      for (int g = 0; g < 4; ++g) acc1 = __builtin_amdgcn_mfma_f32_32x32x16_bf16(vf1[g], pf[g], acc1, 0, 0, 0);
      __builtin_amdgcn_s_setprio(0);
    }
  }

  // ---- split-K combine: wave1 -> LDS, wave0 merges + writes yf ----
  if (w == 1) {
    if (hi == 0) { lm[0][l31] = mrun; lm[1][l31] = lrun; }
#pragma unroll
    for (int r = 0; r < 16; ++r) {
      int d0 = (r & 3) + 8 * (r >> 2) + 4 * hi;
      lacc[d0][l31] = acc0[r];
      lacc[32 + d0][l31] = acc1[r];
    }
  }
  __syncthreads();
  if (w == 0) {
    float m1 = lm[0][l31], l1 = lm[1][l31];
    float M = fmaxf(mrun, m1);
    float f0 = __builtin_amdgcn_exp2f(mrun - M);
    float f1 = __builtin_amdgcn_exp2f(m1 - M);
    float L = lrun * f0 + l1 * f1;
    float inv = __builtin_amdgcn_rcpf(L);
    const int b = bh >> 2, h = bh & 3;
    // yf fragment tile: row = b*2048+q, col = h*64+d
    __bf16* ytile = yf + (((b * 128 + c * 2 + (l31 >> 4)) * 8 + h * 2) * 512)
                       + (l31 & 15) * 32 + hi * 4;
#pragma unroll
    for (int g = 0; g < 4; ++g) {
      float a0[4], a1[4];
#pragma unroll
      for (int i2 = 0; i2 < 4; ++i2) {
        int d0 = i2 + 8 * g + 4 * hi;
        a0[i2] = (acc0[g * 4 + i2] * f0 + lacc[d0][l31] * f1) * inv;
        a1[i2] = (acc1[g * 4 + i2] * f0 + lacc[32 + d0][l31] * f1) * inv;
      }
      uint32_t w0 = cvtpk(a0[0], a0[1]);
      uint32_t w1 = cvtpk(a0[2], a0[3]);
      uint2 st0 = { w0, w1 };
      *(uint2*)(ytile + g * 8) = st0;
      w0 = cvtpk(a1[0], a1[1]);
      w1 = cvtpk(a1[2], a1[3]);
      uint2 st1 = { w0, w1 };
      *(uint2*)(ytile + 512 + g * 8) = st1;   // d+32 -> next col-block tile
    }
  }
}

// ---------------- Proj GEMM: out = y @ W_proj^T (fp32 out) ------------------
// Dense 1KB fragment loads from yf/wpf. XCD-local swizzle.
__global__ __launch_bounds__(256) void proj_gemm(const __bf16* __restrict__ yf,
                                                 const __bf16* __restrict__ wpf,
                                                 float* __restrict__ out) {
  const int lane = threadIdx.x & 63;
  const int ln = lane & 15, kg = lane >> 4;
  const int w = threadIdx.x >> 6;
  const int xs = blockIdx.x & 7;
  const int j = blockIdx.x >> 3;       // 0..31
  const int otile = j & 3;
  const int rt0 = (xs * 8 + (j >> 2)) * 16 + w * 4;
  const int ot0 = otile * 4;
  const int loff = ln * 32 + kg * 8;

  f32x4 acc[4][4] = {};
  for (int cb = 0; cb < 8; ++cb) {
    bf16x8 a[4], wv[4];
#pragma unroll
    for (int i = 0; i < 4; ++i)
      a[i] = *(const bf16x8*)(yf + ((rt0 + i) * 8 + cb) * 512 + loff);
#pragma unroll
    for (int t = 0; t < 4; ++t)
      wv[t] = *(const bf16x8*)(wpf + ((ot0 + t) * 8 + cb) * 512 + loff);
#pragma unroll
    for (int i = 0; i < 4; ++i)
#pragma unroll
      for (int t = 0; t < 4; ++t)
        acc[i][t] = __builtin_amdgcn_mfma_f32_16x16x32_bf16(a[i], wv[t], acc[i][t], 0, 0, 0);
  }
  const int r0 = rt0 * 16;
  const int o0 = ot0 * 16;
#pragma unroll
  for (int i = 0; i < 4; ++i)
#pragma unroll
    for (int t = 0; t < 4; ++t) {
      int o = o0 + t * 16 + ln;
#pragma unroll
      for (int r = 0; r < 4; ++r) {
        int rout = r0 + i * 16 + kg * 4 + r;
        out[rout * 256 + o] = acc[i][t][r];
      }
    }
}

extern "C" void kernel_launch(void* const* d_in, const int* in_sizes, int n_in,
                              void* d_out, int out_size, void* d_ws, size_t ws_size,
                              hipStream_t stream) {
  const float* x = (const float*)d_in[0];
  const float* Wa = (const float*)d_in[1];
  const float* Wp = (const float*)d_in[2];

  char* ws = (char*)d_ws;
  __bf16* xf  = (__bf16*)(ws);                    // 8 MiB  x fragment tiles
  __bf16* qfb = (__bf16*)(ws + 8388608);          // 8 MiB  Qf
  __bf16* kfb = (__bf16*)(ws + 16777216);         // 8 MiB  Kf (pre-scaled)
  __bf16* vfb = (__bf16*)(ws + 25165824);         // 8 MiB  Vf
  __bf16* yf  = (__bf16*)(ws + 33554432);         // 8 MiB  y fragment tiles
  __bf16* waf = (__bf16*)(ws + 41943040);         // 384 KiB W_attn fragment tiles
  __bf16* wpf = (__bf16*)(ws + 42336256);         // 128 KiB W_proj fragment tiles

  cvt3_kernel<<<2176, 256, 0, stream>>>(x, Wa, Wp, xf, waf, wpf);
  qkv_gemm<<<768, 256, 0, stream>>>(xf, waf, qfb, kfb, vfb);
  attn_kernel<<<2048, 128, 0, stream>>>(qfb, kfb, vfb, yf);
  proj_gemm<<<256, 256, 0, stream>>>(yf, wpf, (float*)d_out);
}